// Round 10
// baseline (434.389 us; speedup 1.0000x reference)
//
#include <hip/hip_runtime.h>
#include <hip/hip_fp16.h>

#define NN 50000
#define NE 800000
#define DD 128
#define NL 3
#define BN_EPS 1e-5f

#define NBIN 196      // node bins of 256 nodes
#define BCAP 5120     // per-bin capacity (mean 4096 + ~16 sigma)
#define EB 4096       // edges per binscatter block
#define NB3 ((NE + EB - 1) / EB)   // 196

typedef short bf16x8 __attribute__((ext_vector_type(8)));
typedef float f32x4  __attribute__((ext_vector_type(4)));
typedef unsigned int u32x4 __attribute__((ext_vector_type(4)));

// ---- hi/lo bf16 packing: p = (hi<<16) | lo, value = f(hi) + f(lo) ≈ fp32 ----

__device__ __forceinline__ unsigned int rne16(float v) {
    unsigned int u = __float_as_uint(v);
    return (u + 0x7fffu + ((u >> 16) & 1u)) >> 16;
}
__device__ __forceinline__ unsigned int packf(float v) {
    unsigned int hb = rne16(v);
    float hf = __uint_as_float(hb << 16);
    unsigned int lb = rne16(v - hf);
    return (hb << 16) | lb;
}
__device__ __forceinline__ float unpackf(unsigned int p) {
    return __uint_as_float(p & 0xffff0000u) + __uint_as_float(p << 16);
}

// ---------------- binned CSR build (1024-thread blocks: chain depth 4) ----------------

__global__ __launch_bounds__(1024) void binscatter_kernel(
    const int* __restrict__ src, const int* __restrict__ dst,
    int* __restrict__ bin_cursor, uint2* __restrict__ binned) {
    __shared__ int lhist[NBIN];
    __shared__ int lbase[NBIN];
    __shared__ int lcur[NBIN];
    int t = threadIdx.x;
    for (int i = t; i < NBIN; i += 1024) { lhist[i] = 0; lcur[i] = 0; }
    __syncthreads();
    int base = blockIdx.x * EB;
    int d[4], s[4], b[4];
#pragma unroll
    for (int i = 0; i < 4; ++i) {
        int e = base + t + i * 1024;
        if (e < NE) {
            d[i] = dst[e]; s[i] = src[e]; b[i] = d[i] >> 8;
            atomicAdd(&lhist[b[i]], 1);
        } else b[i] = -1;
    }
    __syncthreads();
    for (int i = t; i < NBIN; i += 1024) {
        int c = lhist[i];
        lbase[i] = c ? atomicAdd(&bin_cursor[i], c) : 0;
    }
    __syncthreads();
#pragma unroll
    for (int i = 0; i < 4; ++i)
        if (b[i] >= 0) {
            int p = lbase[b[i]] + atomicAdd(&lcur[b[i]], 1);
            binned[(size_t)b[i] * BCAP + p] = make_uint2((unsigned)s[i], (unsigned)d[i]);
        }
}

__global__ __launch_bounds__(1024) void bincount_kernel(
    const uint2* __restrict__ binned, const int* __restrict__ bin_cursor,
    int* __restrict__ counts) {
    __shared__ int lcnt[256];
    int bI = blockIdx.x, t = threadIdx.x;
    if (t < 256) lcnt[t] = 0;
    __syncthreads();
    int cnt = bin_cursor[bI];
    const uint2* be = binned + (size_t)bI * BCAP;
    for (int i = t; i < cnt; i += 1024)
        atomicAdd(&lcnt[be[i].y & 255], 1);
    __syncthreads();
    int node = bI * 256 + t;
    if (t < 256 && node < NN) counts[node] = lcnt[t];
}

__global__ void scan1_kernel(const int* __restrict__ counts, int* __restrict__ otmp,
                             int* __restrict__ bsums) {
    __shared__ int sd[1024];
    int t = threadIdx.x;
    int i = blockIdx.x * 1024 + t;
    int v = (i < NN) ? counts[i] : 0;
    sd[t] = v; __syncthreads();
    for (int off = 1; off < 1024; off <<= 1) {
        int tmp = (t >= off) ? sd[t - off] : 0;
        __syncthreads();
        sd[t] += tmp;
        __syncthreads();
    }
    if (i < NN) otmp[i] = sd[t] - v;
    if (t == 1023) bsums[blockIdx.x] = sd[1023];
}

__global__ void scan2_kernel(const int* __restrict__ bsums, int* __restrict__ boffs, int nb) {
    __shared__ int sd[64];
    int t = threadIdx.x;
    int v = (t < nb) ? bsums[t] : 0;
    sd[t] = v; __syncthreads();
    for (int off = 1; off < 64; off <<= 1) {
        int tmp = (t >= off) ? sd[t - off] : 0;
        __syncthreads();
        sd[t] += tmp;
        __syncthreads();
    }
    if (t < nb) boffs[t] = sd[t] - v;
}

__global__ void scan3_kernel(const int* __restrict__ otmp, const int* __restrict__ boffs,
                             int* __restrict__ offsets) {
    int i = blockIdx.x * 1024 + threadIdx.x;
    if (i < NN) offsets[i] = otmp[i] + boffs[blockIdx.x];
}

__global__ __launch_bounds__(1024) void binfill_kernel(
    const uint2* __restrict__ binned, const int* __restrict__ bin_cursor,
    const int* __restrict__ offs, int* __restrict__ csr) {
    __shared__ int lcur[256];
    int bI = blockIdx.x, t = threadIdx.x;
    if (t < 256) lcur[t] = 0;
    __syncthreads();
    int cnt = bin_cursor[bI];
    const uint2* be = binned + (size_t)bI * BCAP;
    for (int i = t; i < cnt; i += 1024) {
        uint2 e = be[i];
        int node = (int)e.y;
        int p = atomicAdd(&lcur[node & 255], 1);
        csr[offs[node] + p] = (int)e.x;
    }
}

// ---------------- fused prep: W split + x -> fp16 ----------------

__global__ void prep_kernel(const float* __restrict__ W1, const float* __restrict__ W2,
                            unsigned short* __restrict__ Whi, unsigned short* __restrict__ Wlo,
                            const float* __restrict__ x, unsigned int* __restrict__ x16) {
    int idx = blockIdx.x * 256 + threadIdx.x;
    if (idx < 6 * 16384) {
        int m = idx >> 14;
        int r = idx & 16383;
        int n = r >> 7, k = r & 127;
        const float* Wsrc = (m < 3) ? (W1 + (size_t)m * 16384) : (W2 + (size_t)(m - 3) * 16384);
        float v = Wsrc[k * DD + n];
        unsigned int hb = rne16(v);
        float hf = __uint_as_float(hb << 16);
        unsigned int lb = rne16(v - hf);
        Whi[idx] = (unsigned short)hb;
        Wlo[idx] = (unsigned short)lb;
    }
    if (idx < NN * 64) {
        float2 v = ((const float2*)x)[idx];
        __half2 h = __float22half2_rn(v);
        x16[idx] = __builtin_bit_cast(unsigned int, h);
    }
}

// ---------------- aggregation: one wave per node, unroll-8 gather (verified) ----------------

template <bool SELF_F32>
__global__ __launch_bounds__(256) void agg_kernel(const void* __restrict__ selfv,
    const unsigned int* __restrict__ h16,
    const int* __restrict__ offsets, const int* __restrict__ counts,
    const int* __restrict__ csr, const float* __restrict__ eps, int l,
    unsigned int* __restrict__ aggp) {
    int wid = (int)((blockIdx.x * 256 + threadIdx.x) >> 6);
    int lane = threadIdx.x & 63;
    if (wid >= NN) return;
    float se = 1.0f + eps[l];
    float ax, ay;
    if (SELF_F32) {
        float2 s = ((const float2*)((const float*)selfv + (size_t)wid * DD))[lane];
        ax = s.x * se; ay = s.y * se;
    } else {
        uint2 s = ((const uint2*)((const unsigned int*)selfv + (size_t)wid * DD))[lane];
        ax = unpackf(s.x) * se; ay = unpackf(s.y) * se;
    }
    int e = offsets[wid];
    int end = e + counts[wid];
    for (; e + 8 <= end; e += 8) {
        int idx[8];
#pragma unroll
        for (int q = 0; q < 8; ++q) idx[q] = csr[e + q];
        unsigned int p[8];
#pragma unroll
        for (int q = 0; q < 8; ++q) p[q] = h16[(size_t)idx[q] * 64 + lane];
#pragma unroll
        for (int q = 0; q < 8; ++q) {
            float2 f = __half22float2(__builtin_bit_cast(__half2, p[q]));
            ax += f.x; ay += f.y;
        }
    }
    for (; e < end; ++e) {
        unsigned int p = h16[(size_t)csr[e] * 64 + lane];
        float2 f = __half22float2(__builtin_bit_cast(__half2, p));
        ax += f.x; ay += f.y;
    }
    uint2 o; o.x = packf(ax); o.y = packf(ay);
    ((uint2*)(aggp + (size_t)wid * DD))[lane] = o;
}

// ---------------- fused MLP, 32-row tiles (structure verified round 4/9) ----------------

__device__ __forceinline__ void gemm_half32(const unsigned int* Al, const bf16x8 (&wh)[4][2],
                                            const bf16x8 (&wl)[4][2], int lane,
                                            f32x4 (&acc)[2][2]) {
#pragma unroll
    for (int r = 0; r < 2; ++r) {
        int rl = r * 16 + (lane & 15);
        int sw = rl & 7;
#pragma unroll
        for (int kb = 0; kb < 4; ++kb) {
            int c0 = kb * 8 + ((lane >> 4) << 1);
            u32x4 q0 = *(const u32x4*)(&Al[rl * DD + ((c0 ^ sw) << 2)]);
            u32x4 q1 = *(const u32x4*)(&Al[rl * DD + (((c0 + 1) ^ sw) << 2)]);
            u32x4 hr, lr;
            hr.x = (q0.x >> 16) | (q0.y & 0xffff0000u);
            hr.y = (q0.z >> 16) | (q0.w & 0xffff0000u);
            hr.z = (q1.x >> 16) | (q1.y & 0xffff0000u);
            hr.w = (q1.z >> 16) | (q1.w & 0xffff0000u);
            lr.x = (q0.x & 0xffffu) | (q0.y << 16);
            lr.y = (q0.z & 0xffffu) | (q0.w << 16);
            lr.z = (q1.x & 0xffffu) | (q1.y << 16);
            lr.w = (q1.z & 0xffffu) | (q1.w << 16);
            bf16x8 ah = __builtin_bit_cast(bf16x8, hr);
            bf16x8 al = __builtin_bit_cast(bf16x8, lr);
#pragma unroll
            for (int nb = 0; nb < 2; ++nb) {
                acc[r][nb] = __builtin_amdgcn_mfma_f32_16x16x32_bf16(ah, wh[kb][nb], acc[r][nb], 0, 0, 0);
                acc[r][nb] = __builtin_amdgcn_mfma_f32_16x16x32_bf16(ah, wl[kb][nb], acc[r][nb], 0, 0, 0);
                acc[r][nb] = __builtin_amdgcn_mfma_f32_16x16x32_bf16(al, wh[kb][nb], acc[r][nb], 0, 0, 0);
            }
        }
    }
}

__global__ __launch_bounds__(256, 5) void mlp_kernel(
    const unsigned int* __restrict__ Ap,
    const unsigned short* __restrict__ Wh1, const unsigned short* __restrict__ Wl1,
    const unsigned short* __restrict__ Wh2, const unsigned short* __restrict__ Wl2,
    const float* __restrict__ b1v, const float* __restrict__ gamma,
    const float* __restrict__ beta, const float* __restrict__ mean,
    const float* __restrict__ var, const float* __restrict__ b2v,
    void* __restrict__ outp, unsigned short* __restrict__ out16, int last) {
    __shared__ unsigned int Al[32 * DD];   // 16 KB; A tile, then z1
    int t = threadIdx.x;
    int lane = t & 63, w = t >> 6;
    int r0 = blockIdx.x * 32;
    int cb = w * 32;
    int nfrag = lane & 15;
    int kfrag = (lane >> 4) << 3;

    // W1 fragments (registers reused for W2 later)
    bf16x8 wh[4][2], wl[4][2];
#pragma unroll
    for (int kb = 0; kb < 4; ++kb)
#pragma unroll
        for (int nb = 0; nb < 2; ++nb) {
            size_t off = (size_t)(cb + nb * 16 + nfrag) * DD + kb * 32 + kfrag;
            wh[kb][nb] = *(const bf16x8*)(Wh1 + off);
            wl[kb][nb] = *(const bf16x8*)(Wl1 + off);
        }

    // stage A tile (32 rows x 128 u32), 16B-chunk XOR swizzle by (row&7)
    {
        int cchunk = t & 31;
#pragma unroll
        for (int it = 0; it < 4; ++it) {
            int rl = it * 8 + (t >> 5);
            int rg = r0 + rl; if (rg > NN - 1) rg = NN - 1;
            u32x4 v = *(const u32x4*)(Ap + (size_t)rg * DD + cchunk * 4);
            *(u32x4*)(&Al[rl * DD + ((cchunk ^ (rl & 7)) << 2)]) = v;
        }
    }
    __syncthreads();

    f32x4 acc[2][2];
#pragma unroll
    for (int r = 0; r < 2; ++r)
#pragma unroll
        for (int nb = 0; nb < 2; ++nb) acc[r][nb] = (f32x4){0.f, 0.f, 0.f, 0.f};

    gemm_half32(Al, wh, wl, lane, acc);

    // W2 fragments into the same registers (W1 dead)
#pragma unroll
    for (int kb = 0; kb < 4; ++kb)
#pragma unroll
        for (int nb = 0; nb < 2; ++nb) {
            size_t off = (size_t)(cb + nb * 16 + nfrag) * DD + kb * 32 + kfrag;
            wh[kb][nb] = *(const bf16x8*)(Wh2 + off);
            wl[kb][nb] = *(const bf16x8*)(Wl2 + off);
        }

    __syncthreads();   // WAR: all Al reads done before z1 overwrite

    // epilogue1: bias+BN+ReLU, pack, write z1 into Al (same swizzle)
#pragma unroll
    for (int nb = 0; nb < 2; ++nb) {
        int col = cb + nb * 16 + nfrag;
        float bs = b1v[col];
        float iv = rsqrtf(var[col] + BN_EPS);
        float sc = iv * gamma[col];
        float sh = beta[col] - mean[col] * sc;
#pragma unroll
        for (int r = 0; r < 2; ++r)
#pragma unroll
            for (int j = 0; j < 4; ++j) {
                int row = r * 16 + ((lane >> 4) << 2) + j;
                float v = fmaxf(fmaf(acc[r][nb][j] + bs, sc, sh), 0.0f);
                Al[row * DD + ((((col >> 2) ^ (row & 7)) << 2) | (col & 3))] = packf(v);
            }
    }
    __syncthreads();

#pragma unroll
    for (int r = 0; r < 2; ++r)
#pragma unroll
        for (int nb = 0; nb < 2; ++nb) acc[r][nb] = (f32x4){0.f, 0.f, 0.f, 0.f};

    gemm_half32(Al, wh, wl, lane, acc);

    // epilogue2: bias (+ReLU -> packed + fp16 | fp32 store)
#pragma unroll
    for (int nb = 0; nb < 2; ++nb) {
        int col = cb + nb * 16 + nfrag;
        float bs = b2v[col];
#pragma unroll
        for (int r = 0; r < 2; ++r)
#pragma unroll
            for (int j = 0; j < 4; ++j) {
                int orow = r0 + r * 16 + ((lane >> 4) << 2) + j;
                if (orow < NN) {
                    float v = acc[r][nb][j] + bs;
                    if (last) {
                        ((float*)outp)[(size_t)orow * DD + col] = v;
                    } else {
                        v = fmaxf(v, 0.0f);
                        ((unsigned int*)outp)[(size_t)orow * DD + col] = packf(v);
                        out16[(size_t)orow * DD + col] =
                            __builtin_bit_cast(unsigned short, __float2half_rn(v));
                    }
                }
            }
    }
}

// ---------------- launch ----------------

extern "C" void kernel_launch(void* const* d_in, const int* in_sizes, int n_in,
                              void* d_out, int out_size, void* d_ws, size_t ws_size,
                              hipStream_t stream) {
    const float* x     = (const float*)d_in[0];
    const int*   eidx  = (const int*)d_in[1];
    const float* W1    = (const float*)d_in[2];
    const float* b1    = (const float*)d_in[3];
    const float* gamma = (const float*)d_in[4];
    const float* beta  = (const float*)d_in[5];
    const float* bnm   = (const float*)d_in[6];
    const float* bnv   = (const float*)d_in[7];
    const float* W2    = (const float*)d_in[8];
    const float* b2    = (const float*)d_in[9];
    const float* eps   = (const float*)d_in[10];
    float* out = (float*)d_out;

    const int* src = eidx;
    const int* dst = eidx + NE;

    char* wsp = (char*)d_ws;
    unsigned int* bufA = (unsigned int*)wsp;  wsp += (size_t)NN * DD * 4;
    unsigned int* bufB = (unsigned int*)wsp;  wsp += (size_t)NN * DD * 4;
    unsigned int* x16  = (unsigned int*)wsp;  wsp += (size_t)NN * DD * 2;
    unsigned int* h16  = (unsigned int*)wsp;  wsp += (size_t)NN * DD * 2;
    uint2* binned      = (uint2*)wsp;         wsp += (size_t)NBIN * BCAP * 8;
    int* csr    = (int*)wsp;                  wsp += (size_t)NE * 4;
    int* counts = (int*)wsp;                  wsp += (size_t)NN * 4;
    int* offs   = (int*)wsp;                  wsp += (size_t)NN * 4;
    int* bin_cursor = (int*)wsp;              wsp += (size_t)NBIN * 4;
    unsigned short* Whi = (unsigned short*)wsp; wsp += (size_t)6 * 16384 * 2;
    unsigned short* Wlo = (unsigned short*)wsp; wsp += (size_t)6 * 16384 * 2;
    int* bsums  = (int*)wsp;                  wsp += 64 * 4;
    int* boffs  = (int*)wsp;                  wsp += 64 * 4;

    hipMemsetAsync(bin_cursor, 0, (size_t)NBIN * 4, stream);

    prep_kernel<<<(NN * 64 + 255) / 256, 256, 0, stream>>>(W1, W2, Whi, Wlo, x, x16);

    int nbScan = (NN + 1023) / 1024;
    binscatter_kernel<<<NB3, 1024, 0, stream>>>(src, dst, bin_cursor, binned);
    bincount_kernel<<<NBIN, 1024, 0, stream>>>(binned, bin_cursor, counts);
    scan1_kernel<<<nbScan, 1024, 0, stream>>>(counts, offs, bsums);
    scan2_kernel<<<1, 64, 0, stream>>>(bsums, boffs, nbScan);
    scan3_kernel<<<nbScan, 1024, 0, stream>>>(offs, boffs, offs);
    binfill_kernel<<<NBIN, 1024, 0, stream>>>(binned, bin_cursor, offs, csr);

    int aggBlocks = (NN * 64 + 255) / 256;
    int mlpBlocks = (NN + 31) / 32;

    // L0: agg(x fp32 self, x16 nbr) -> bufA ; mlp bufA -> bufB(packed) + h16
    // L1: agg(bufB self, h16 nbr)   -> bufA ; mlp bufA -> bufB(packed) + h16
    // L2: agg(bufB self, h16 nbr)   -> bufA ; mlp bufA -> out (fp32)
    for (int l = 0; l < NL; ++l) {
        if (l == 0)
            agg_kernel<true><<<aggBlocks, 256, 0, stream>>>(x, x16, offs, counts, csr, eps, l, bufA);
        else
            agg_kernel<false><<<aggBlocks, 256, 0, stream>>>(bufB, h16, offs, counts, csr, eps, l, bufA);
        int last = (l == NL - 1);
        mlp_kernel<<<mlpBlocks, 256, 0, stream>>>(
            bufA,
            Whi + (size_t)l * 16384, Wlo + (size_t)l * 16384,
            Whi + (size_t)(3 + l) * 16384, Wlo + (size_t)(3 + l) * 16384,
            b1 + (size_t)l * DD, gamma + (size_t)l * DD, beta + (size_t)l * DD,
            bnm + (size_t)l * DD, bnv + (size_t)l * DD, b2 + (size_t)l * DD,
            last ? (void*)out : (void*)bufB, (unsigned short*)h16, last);
    }
}

// Round 11
// 353.852 us; speedup vs baseline: 1.2276x; 1.2276x over previous
//
#include <hip/hip_runtime.h>
#include <hip/hip_fp16.h>

#define NN 50000
#define NE 800000
#define DD 128
#define NL 3
#define BN_EPS 1e-5f

#define NBIN 196      // node bins of 256 nodes
#define BCAP 5120     // per-bin capacity (mean 4096 + ~16 sigma)
#define EB 4096       // edges per binscatter block
#define NB3 ((NE + EB - 1) / EB)   // 196

typedef short bf16x8 __attribute__((ext_vector_type(8)));
typedef float f32x4  __attribute__((ext_vector_type(4)));
typedef unsigned int u32x4 __attribute__((ext_vector_type(4)));

// ---- hi/lo bf16 packing: p = (hi<<16) | lo, value = f(hi) + f(lo) ≈ fp32 ----

__device__ __forceinline__ unsigned int rne16(float v) {
    unsigned int u = __float_as_uint(v);
    return (u + 0x7fffu + ((u >> 16) & 1u)) >> 16;
}
__device__ __forceinline__ unsigned int packf(float v) {
    unsigned int hb = rne16(v);
    float hf = __uint_as_float(hb << 16);
    unsigned int lb = rne16(v - hf);
    return (hb << 16) | lb;
}
__device__ __forceinline__ float unpackf(unsigned int p) {
    return __uint_as_float(p & 0xffff0000u) + __uint_as_float(p << 16);
}

// ---------------- binned CSR build (1024-thread blocks, verified round 10) ----------------

__global__ __launch_bounds__(1024) void binscatter_kernel(
    const int* __restrict__ src, const int* __restrict__ dst,
    int* __restrict__ bin_cursor, uint2* __restrict__ binned) {
    __shared__ int lhist[NBIN];
    __shared__ int lbase[NBIN];
    __shared__ int lcur[NBIN];
    int t = threadIdx.x;
    for (int i = t; i < NBIN; i += 1024) { lhist[i] = 0; lcur[i] = 0; }
    __syncthreads();
    int base = blockIdx.x * EB;
    int d[4], s[4], b[4];
#pragma unroll
    for (int i = 0; i < 4; ++i) {
        int e = base + t + i * 1024;
        if (e < NE) {
            d[i] = dst[e]; s[i] = src[e]; b[i] = d[i] >> 8;
            atomicAdd(&lhist[b[i]], 1);
        } else b[i] = -1;
    }
    __syncthreads();
    for (int i = t; i < NBIN; i += 1024) {
        int c = lhist[i];
        lbase[i] = c ? atomicAdd(&bin_cursor[i], c) : 0;
    }
    __syncthreads();
#pragma unroll
    for (int i = 0; i < 4; ++i)
        if (b[i] >= 0) {
            int p = lbase[b[i]] + atomicAdd(&lcur[b[i]], 1);
            binned[(size_t)b[i] * BCAP + p] = make_uint2((unsigned)s[i], (unsigned)d[i]);
        }
}

__global__ __launch_bounds__(1024) void bincount_kernel(
    const uint2* __restrict__ binned, const int* __restrict__ bin_cursor,
    int* __restrict__ counts) {
    __shared__ int lcnt[256];
    int bI = blockIdx.x, t = threadIdx.x;
    if (t < 256) lcnt[t] = 0;
    __syncthreads();
    int cnt = bin_cursor[bI];
    const uint2* be = binned + (size_t)bI * BCAP;
    for (int i = t; i < cnt; i += 1024)
        atomicAdd(&lcnt[be[i].y & 255], 1);
    __syncthreads();
    int node = bI * 256 + t;
    if (t < 256 && node < NN) counts[node] = lcnt[t];
}

__global__ void scan1_kernel(const int* __restrict__ counts, int* __restrict__ otmp,
                             int* __restrict__ bsums) {
    __shared__ int sd[1024];
    int t = threadIdx.x;
    int i = blockIdx.x * 1024 + t;
    int v = (i < NN) ? counts[i] : 0;
    sd[t] = v; __syncthreads();
    for (int off = 1; off < 1024; off <<= 1) {
        int tmp = (t >= off) ? sd[t - off] : 0;
        __syncthreads();
        sd[t] += tmp;
        __syncthreads();
    }
    if (i < NN) otmp[i] = sd[t] - v;
    if (t == 1023) bsums[blockIdx.x] = sd[1023];
}

__global__ void scan2_kernel(const int* __restrict__ bsums, int* __restrict__ boffs, int nb) {
    __shared__ int sd[64];
    int t = threadIdx.x;
    int v = (t < nb) ? bsums[t] : 0;
    sd[t] = v; __syncthreads();
    for (int off = 1; off < 64; off <<= 1) {
        int tmp = (t >= off) ? sd[t - off] : 0;
        __syncthreads();
        sd[t] += tmp;
        __syncthreads();
    }
    if (t < nb) boffs[t] = sd[t] - v;
}

__global__ void scan3_kernel(const int* __restrict__ otmp, const int* __restrict__ boffs,
                             int* __restrict__ offsets) {
    int i = blockIdx.x * 1024 + threadIdx.x;
    if (i < NN) offsets[i] = otmp[i] + boffs[blockIdx.x];
}

__global__ __launch_bounds__(1024) void binfill_kernel(
    const uint2* __restrict__ binned, const int* __restrict__ bin_cursor,
    const int* __restrict__ offs, int* __restrict__ csr) {
    __shared__ int lcur[256];
    int bI = blockIdx.x, t = threadIdx.x;
    if (t < 256) lcur[t] = 0;
    __syncthreads();
    int cnt = bin_cursor[bI];
    const uint2* be = binned + (size_t)bI * BCAP;
    for (int i = t; i < cnt; i += 1024) {
        uint2 e = be[i];
        int node = (int)e.y;
        int p = atomicAdd(&lcur[node & 255], 1);
        csr[offs[node] + p] = (int)e.x;
    }
}

// ---------------- fused prep: W split + x -> fp16 (verified round 10) ----------------

__global__ void prep_kernel(const float* __restrict__ W1, const float* __restrict__ W2,
                            unsigned short* __restrict__ Whi, unsigned short* __restrict__ Wlo,
                            const float* __restrict__ x, unsigned int* __restrict__ x16) {
    int idx = blockIdx.x * 256 + threadIdx.x;
    if (idx < 6 * 16384) {
        int m = idx >> 14;
        int r = idx & 16383;
        int n = r >> 7, k = r & 127;
        const float* Wsrc = (m < 3) ? (W1 + (size_t)m * 16384) : (W2 + (size_t)(m - 3) * 16384);
        float v = Wsrc[k * DD + n];
        unsigned int hb = rne16(v);
        float hf = __uint_as_float(hb << 16);
        unsigned int lb = rne16(v - hf);
        Whi[idx] = (unsigned short)hb;
        Wlo[idx] = (unsigned short)lb;
    }
    if (idx < NN * 64) {
        float2 v = ((const float2*)x)[idx];
        __half2 h = __float22half2_rn(v);
        x16[idx] = __builtin_bit_cast(unsigned int, h);
    }
}

// ---------------- aggregation: one wave per node, unroll-8 gather (verified) ----------------

template <bool SELF_F32>
__global__ __launch_bounds__(256) void agg_kernel(const void* __restrict__ selfv,
    const unsigned int* __restrict__ h16,
    const int* __restrict__ offsets, const int* __restrict__ counts,
    const int* __restrict__ csr, const float* __restrict__ eps, int l,
    unsigned int* __restrict__ aggp) {
    int wid = (int)((blockIdx.x * 256 + threadIdx.x) >> 6);
    int lane = threadIdx.x & 63;
    if (wid >= NN) return;
    float se = 1.0f + eps[l];
    float ax, ay;
    if (SELF_F32) {
        float2 s = ((const float2*)((const float*)selfv + (size_t)wid * DD))[lane];
        ax = s.x * se; ay = s.y * se;
    } else {
        uint2 s = ((const uint2*)((const unsigned int*)selfv + (size_t)wid * DD))[lane];
        ax = unpackf(s.x) * se; ay = unpackf(s.y) * se;
    }
    int e = offsets[wid];
    int end = e + counts[wid];
    for (; e + 8 <= end; e += 8) {
        int idx[8];
#pragma unroll
        for (int q = 0; q < 8; ++q) idx[q] = csr[e + q];
        unsigned int p[8];
#pragma unroll
        for (int q = 0; q < 8; ++q) p[q] = h16[(size_t)idx[q] * 64 + lane];
#pragma unroll
        for (int q = 0; q < 8; ++q) {
            float2 f = __half22float2(__builtin_bit_cast(__half2, p[q]));
            ax += f.x; ay += f.y;
        }
    }
    for (; e < end; ++e) {
        unsigned int p = h16[(size_t)csr[e] * 64 + lane];
        float2 f = __half22float2(__builtin_bit_cast(__half2, p));
        ax += f.x; ay += f.y;
    }
    uint2 o; o.x = packf(ax); o.y = packf(ay);
    ((uint2*)(aggp + (size_t)wid * DD))[lane] = o;
}

// ---------------- fused MLP, 64-row tiles (exact verified round 9 version) ----------------

__device__ __forceinline__ void gemm_half(const unsigned int* Al, const bf16x8 (&wh)[4][2],
                                          const bf16x8 (&wl)[4][2], int lane,
                                          f32x4 (&acc)[4][2]) {
#pragma unroll
    for (int r = 0; r < 4; ++r) {
        int rl = r * 16 + (lane & 15);
        int sw = rl & 7;
#pragma unroll
        for (int kb = 0; kb < 4; ++kb) {
            int c0 = kb * 8 + ((lane >> 4) << 1);
            u32x4 q0 = *(const u32x4*)(&Al[rl * DD + ((c0 ^ sw) << 2)]);
            u32x4 q1 = *(const u32x4*)(&Al[rl * DD + (((c0 + 1) ^ sw) << 2)]);
            u32x4 hr, lr;
            hr.x = (q0.x >> 16) | (q0.y & 0xffff0000u);
            hr.y = (q0.z >> 16) | (q0.w & 0xffff0000u);
            hr.z = (q1.x >> 16) | (q1.y & 0xffff0000u);
            hr.w = (q1.z >> 16) | (q1.w & 0xffff0000u);
            lr.x = (q0.x & 0xffffu) | (q0.y << 16);
            lr.y = (q0.z & 0xffffu) | (q0.w << 16);
            lr.z = (q1.x & 0xffffu) | (q1.y << 16);
            lr.w = (q1.z & 0xffffu) | (q1.w << 16);
            bf16x8 ah = __builtin_bit_cast(bf16x8, hr);
            bf16x8 al = __builtin_bit_cast(bf16x8, lr);
#pragma unroll
            for (int nb = 0; nb < 2; ++nb) {
                acc[r][nb] = __builtin_amdgcn_mfma_f32_16x16x32_bf16(ah, wh[kb][nb], acc[r][nb], 0, 0, 0);
                acc[r][nb] = __builtin_amdgcn_mfma_f32_16x16x32_bf16(ah, wl[kb][nb], acc[r][nb], 0, 0, 0);
                acc[r][nb] = __builtin_amdgcn_mfma_f32_16x16x32_bf16(al, wh[kb][nb], acc[r][nb], 0, 0, 0);
            }
        }
    }
}

__global__ __launch_bounds__(256, 3) void mlp_kernel(
    const unsigned int* __restrict__ Ap,
    const unsigned short* __restrict__ Wh1, const unsigned short* __restrict__ Wl1,
    const unsigned short* __restrict__ Wh2, const unsigned short* __restrict__ Wl2,
    const float* __restrict__ b1v, const float* __restrict__ gamma,
    const float* __restrict__ beta, const float* __restrict__ mean,
    const float* __restrict__ var, const float* __restrict__ b2v,
    void* __restrict__ outp, unsigned short* __restrict__ out16, int last) {
    __shared__ unsigned int Al[64 * DD];   // 32 KB; A tile, then z1
    int t = threadIdx.x;
    int lane = t & 63, w = t >> 6;
    int r0 = blockIdx.x * 64;
    int cb = w * 32;
    int nfrag = lane & 15;
    int kfrag = (lane >> 4) << 3;

    // W1 fragments (registers reused for W2 later)
    bf16x8 wh[4][2], wl[4][2];
#pragma unroll
    for (int kb = 0; kb < 4; ++kb)
#pragma unroll
        for (int nb = 0; nb < 2; ++nb) {
            size_t off = (size_t)(cb + nb * 16 + nfrag) * DD + kb * 32 + kfrag;
            wh[kb][nb] = *(const bf16x8*)(Wh1 + off);
            wl[kb][nb] = *(const bf16x8*)(Wl1 + off);
        }

    // stage A tile (64 rows x 128 u32), 16B-chunk XOR swizzle by (row&7)
    {
        int cchunk = t & 31;
#pragma unroll
        for (int it = 0; it < 8; ++it) {
            int rl = it * 8 + (t >> 5);
            int rg = r0 + rl; if (rg > NN - 1) rg = NN - 1;
            u32x4 v = *(const u32x4*)(Ap + (size_t)rg * DD + cchunk * 4);
            *(u32x4*)(&Al[rl * DD + ((cchunk ^ (rl & 7)) << 2)]) = v;
        }
    }
    __syncthreads();

    f32x4 acc[4][2];
#pragma unroll
    for (int r = 0; r < 4; ++r)
#pragma unroll
        for (int nb = 0; nb < 2; ++nb) acc[r][nb] = (f32x4){0.f, 0.f, 0.f, 0.f};

    gemm_half(Al, wh, wl, lane, acc);

    // W2 fragments into the same registers (W1 dead)
#pragma unroll
    for (int kb = 0; kb < 4; ++kb)
#pragma unroll
        for (int nb = 0; nb < 2; ++nb) {
            size_t off = (size_t)(cb + nb * 16 + nfrag) * DD + kb * 32 + kfrag;
            wh[kb][nb] = *(const bf16x8*)(Wh2 + off);
            wl[kb][nb] = *(const bf16x8*)(Wl2 + off);
        }

    __syncthreads();   // WAR: all Al reads done before z1 overwrite

    // epilogue1: bias+BN+ReLU, pack, write z1 into Al (same swizzle)
#pragma unroll
    for (int nb = 0; nb < 2; ++nb) {
        int col = cb + nb * 16 + nfrag;
        float bs = b1v[col];
        float iv = rsqrtf(var[col] + BN_EPS);
        float sc = iv * gamma[col];
        float sh = beta[col] - mean[col] * sc;
#pragma unroll
        for (int r = 0; r < 4; ++r)
#pragma unroll
            for (int j = 0; j < 4; ++j) {
                int row = r * 16 + ((lane >> 4) << 2) + j;
                float v = fmaxf(fmaf(acc[r][nb][j] + bs, sc, sh), 0.0f);
                Al[row * DD + ((((col >> 2) ^ (row & 7)) << 2) | (col & 3))] = packf(v);
            }
    }
    __syncthreads();

#pragma unroll
    for (int r = 0; r < 4; ++r)
#pragma unroll
        for (int nb = 0; nb < 2; ++nb) acc[r][nb] = (f32x4){0.f, 0.f, 0.f, 0.f};

    gemm_half(Al, wh, wl, lane, acc);

    // epilogue2: bias (+ReLU -> packed + fp16 | fp32 store)
#pragma unroll
    for (int nb = 0; nb < 2; ++nb) {
        int col = cb + nb * 16 + nfrag;
        float bs = b2v[col];
#pragma unroll
        for (int r = 0; r < 4; ++r)
#pragma unroll
            for (int j = 0; j < 4; ++j) {
                int orow = r0 + r * 16 + ((lane >> 4) << 2) + j;
                if (orow < NN) {
                    float v = acc[r][nb][j] + bs;
                    if (last) {
                        ((float*)outp)[(size_t)orow * DD + col] = v;
                    } else {
                        v = fmaxf(v, 0.0f);
                        ((unsigned int*)outp)[(size_t)orow * DD + col] = packf(v);
                        out16[(size_t)orow * DD + col] =
                            __builtin_bit_cast(unsigned short, __float2half_rn(v));
                    }
                }
            }
    }
}

// ---------------- launch ----------------

extern "C" void kernel_launch(void* const* d_in, const int* in_sizes, int n_in,
                              void* d_out, int out_size, void* d_ws, size_t ws_size,
                              hipStream_t stream) {
    const float* x     = (const float*)d_in[0];
    const int*   eidx  = (const int*)d_in[1];
    const float* W1    = (const float*)d_in[2];
    const float* b1    = (const float*)d_in[3];
    const float* gamma = (const float*)d_in[4];
    const float* beta  = (const float*)d_in[5];
    const float* bnm   = (const float*)d_in[6];
    const float* bnv   = (const float*)d_in[7];
    const float* W2    = (const float*)d_in[8];
    const float* b2    = (const float*)d_in[9];
    const float* eps   = (const float*)d_in[10];
    float* out = (float*)d_out;

    const int* src = eidx;
    const int* dst = eidx + NE;

    char* wsp = (char*)d_ws;
    unsigned int* bufA = (unsigned int*)wsp;  wsp += (size_t)NN * DD * 4;
    unsigned int* bufB = (unsigned int*)wsp;  wsp += (size_t)NN * DD * 4;
    unsigned int* x16  = (unsigned int*)wsp;  wsp += (size_t)NN * DD * 2;
    unsigned int* h16  = (unsigned int*)wsp;  wsp += (size_t)NN * DD * 2;
    uint2* binned      = (uint2*)wsp;         wsp += (size_t)NBIN * BCAP * 8;
    int* csr    = (int*)wsp;                  wsp += (size_t)NE * 4;
    int* counts = (int*)wsp;                  wsp += (size_t)NN * 4;
    int* offs   = (int*)wsp;                  wsp += (size_t)NN * 4;
    int* bin_cursor = (int*)wsp;              wsp += (size_t)NBIN * 4;
    unsigned short* Whi = (unsigned short*)wsp; wsp += (size_t)6 * 16384 * 2;
    unsigned short* Wlo = (unsigned short*)wsp; wsp += (size_t)6 * 16384 * 2;
    int* bsums  = (int*)wsp;                  wsp += 64 * 4;
    int* boffs  = (int*)wsp;                  wsp += 64 * 4;

    hipMemsetAsync(bin_cursor, 0, (size_t)NBIN * 4, stream);

    prep_kernel<<<(NN * 64 + 255) / 256, 256, 0, stream>>>(W1, W2, Whi, Wlo, x, x16);

    int nbScan = (NN + 1023) / 1024;
    binscatter_kernel<<<NB3, 1024, 0, stream>>>(src, dst, bin_cursor, binned);
    bincount_kernel<<<NBIN, 1024, 0, stream>>>(binned, bin_cursor, counts);
    scan1_kernel<<<nbScan, 1024, 0, stream>>>(counts, offs, bsums);
    scan2_kernel<<<1, 64, 0, stream>>>(bsums, boffs, nbScan);
    scan3_kernel<<<nbScan, 1024, 0, stream>>>(offs, boffs, offs);
    binfill_kernel<<<NBIN, 1024, 0, stream>>>(binned, bin_cursor, offs, csr);

    int aggBlocks = (NN * 64 + 255) / 256;
    int mlpBlocks = (NN + 63) / 64;

    // L0: agg(x fp32 self, x16 nbr) -> bufA ; mlp bufA -> bufB(packed) + h16
    // L1: agg(bufB self, h16 nbr)   -> bufA ; mlp bufA -> bufB(packed) + h16
    // L2: agg(bufB self, h16 nbr)   -> bufA ; mlp bufA -> out (fp32)
    for (int l = 0; l < NL; ++l) {
        if (l == 0)
            agg_kernel<true><<<aggBlocks, 256, 0, stream>>>(x, x16, offs, counts, csr, eps, l, bufA);
        else
            agg_kernel<false><<<aggBlocks, 256, 0, stream>>>(bufB, h16, offs, counts, csr, eps, l, bufA);
        int last = (l == NL - 1);
        mlp_kernel<<<mlpBlocks, 256, 0, stream>>>(
            bufA,
            Whi + (size_t)l * 16384, Wlo + (size_t)l * 16384,
            Whi + (size_t)(3 + l) * 16384, Wlo + (size_t)(3 + l) * 16384,
            b1 + (size_t)l * DD, gamma + (size_t)l * DD, beta + (size_t)l * DD,
            bnm + (size_t)l * DD, bnv + (size_t)l * DD, b2 + (size_t)l * DD,
            last ? (void*)out : (void*)bufB, (unsigned short*)h16, last);
    }
}